// Round 7
// baseline (24.207 us; speedup 1.0000x reference)
//
#include <hip/hip_runtime.h>
#include <hip/hip_bf16.h>

// Problem constants: B=8, G=2048, K=32, N=6, C=64; fourier_B is (7,32)
// out: (B, 128, G) float32
//
// Algebraic simplifications (validated):
//  1) up/down == mean_k(knn_f) since e_x is constant over k, so
//     kl_raw = 2*mean_k(sin^5/cos^5(2*pi*x)).
//  2) x = fB . [p, p x n, p.n] is linear in p:
//     x = e0*p0 + e1*p1 + e2*p2 with per-channel e precomputed from fB and n.
//
// Round 7: block = 16 consecutive bg (4 waves x 4 bg). Results staged in an
// LDS tile klbuf[128][17] and stored cooperatively as float4 rows -> every
// 64B line fully written (16x fewer write transactions than per-wave scatter).

#if __has_builtin(__builtin_amdgcn_fractf)
  #define FRACT(x) __builtin_amdgcn_fractf(x)
#else
  #define FRACT(x) ((x) - floorf(x))
#endif

__global__ __launch_bounds__(256, 8) void line_pass1(
    const float* __restrict__ lc_x,     // (B,G,64)
    const float* __restrict__ knn_x,    // (B,G,32,6)
    const float* __restrict__ fB,       // (7,32)
    float* __restrict__ out)            // (B,128,G)
{
    const int wave = threadIdx.x >> 6;
    const int lane = threadIdx.x & 63;
    const int half = lane >> 5;                 // 0: even k, 1: odd k
    const int jj   = lane & 31;                 // channel
    // bijective XCD swizzle: 1024 blocks, 8 XCDs, 128 blocks each
    const int sbid = (blockIdx.x & 7) * 128 + (blockIdx.x >> 3);
    const int bg0  = sbid * 16;                 // 16 consecutive bg per block
    const int b    = bg0 >> 11;
    const int g0   = bg0 & 2047;                // 16-aligned, never crosses b

    __shared__ __align__(16) float4 lv[4][4][32];   // [wave][i][k] p-vectors
    __shared__ float klbuf[128][17];                // [channel][col], pad 17

    // fourier_B column for this lane's channel
    const float fb0 = fB[0*32 + jj];
    const float fb1 = fB[1*32 + jj];
    const float fb2 = fB[2*32 + jj];
    const float fb3 = fB[3*32 + jj];
    const float fb4 = fB[4*32 + jj];
    const float fb5 = fB[5*32 + jj];
    const float fb6 = fB[6*32 + jj];

    // ---- prefetch all global data for this wave's 4 bg
    float lcv[4], pp0[4], pp1[4], pp2[4];
    #pragma unroll
    for (int i = 0; i < 4; ++i) {
        const int bg = bg0 + wave * 4 + i;
        lcv[i] = lc_x[(size_t)bg * 64 + lane];          // coalesced
        if (half == 0) {
            const float* kp = knn_x + (size_t)bg * 192 + jj * 6;
            pp0[i] = kp[3]; pp1[i] = kp[4]; pp2[i] = kp[5];
        }
    }
    // stage p-vectors for all 4 bg (wave-local)
    #pragma unroll
    for (int i = 0; i < 4; ++i) {
        if (half == 0)
            lv[wave][i][jj] = make_float4(pp0[i], pp1[i], pp2[i], 0.0f);
    }
    asm volatile("s_waitcnt lgkmcnt(0)" ::: "memory");  // wave-local, no barrier

    #pragma unroll
    for (int i = 0; i < 4; ++i) {
        const int bg  = bg0 + wave * 4 + i;
        const int col = wave * 4 + i;
        const float* lcr = lc_x + (size_t)bg * 64;
        const float n0 = lcr[3];                        // uniform -> s_load
        const float n1 = lcr[4];
        const float n2 = lcr[5];

        // lc_line: normalize over C=64
        float ssum = lcv[i] * lcv[i];
        #pragma unroll
        for (int off = 32; off; off >>= 1) ssum += __shfl_xor(ssum, off, 64);
        klbuf[64 + lane][col] = lcv[i] / sqrtf(ssum);   // pad-17: conflict-free

        // effective projection vector: x = e0*p0 + e1*p1 + e2*p2
        const float e0 = fmaf(fb6, n0, fmaf(fb5,  n1, fmaf(fb4, -n2, fb0)));
        const float e1 = fmaf(fb6, n1, fmaf(fb5, -n0, fmaf(fb3,  n2, fb1)));
        const float e2 = fmaf(fb6, n2, fmaf(fb4,  n0, fmaf(fb3, -n1, fb2)));

        float accS0 = 0.f, accS1 = 0.f, accC0 = 0.f, accC1 = 0.f;
        const float4* myk = &lv[wave][i][half];         // k = 2*t + half
        #pragma unroll
        for (int t = 0; t < 16; ++t) {
            const float4 p = myk[2 * t];                // broadcast ds_read_b128
            const float x = fmaf(e2, p.z, fmaf(e1, p.y, e0 * p.x));
            const float ts = FRACT(x);                  // revolutions in [0,1)
            const float tc = FRACT(x + 0.25f);
            const float s  = __builtin_amdgcn_sinf(ts); // sin(2*pi*x)
            const float cq = __builtin_amdgcn_sinf(tc); // cos(2*pi*x)
            const float s2 = s * s,   s4 = s2 * s2;
            const float q2 = cq * cq, q4 = q2 * q2;
            if (t & 1) { accS1 = fmaf(s4, s, accS1); accC1 = fmaf(q4, cq, accC1); }
            else       { accS0 = fmaf(s4, s, accS0); accC0 = fmaf(q4, cq, accC0); }
        }
        // merge even-k / odd-k halves across the lane32 boundary
        const float aS = accS0 + accS1;
        const float aC = accC0 + accC1;
        const float totS = aS + __shfl_xor(aS, 32, 64);
        const float totC = aC + __shfl_xor(aC, 32, 64);
        klbuf[lane][col] = (half ? totC : totS) * 0.0625f;  // 2*mean_k
    }

    __syncthreads();

    // cooperative coalesced store: thread t -> row c=t>>1, cols (t&1)*8..+7
    const int c  = threadIdx.x >> 1;
    const int j0 = (threadIdx.x & 1) * 8;
    float o[8];
    #pragma unroll
    for (int q = 0; q < 8; ++q) o[q] = klbuf[c][j0 + q];
    float* dst = out + ((size_t)b * 128 + c) * 2048 + g0 + j0;
    *(float4*)(dst + 0) = make_float4(o[0], o[1], o[2], o[3]);
    *(float4*)(dst + 4) = make_float4(o[4], o[5], o[6], o[7]);
}

__global__ __launch_bounds__(256) void line_pass2(float* __restrict__ out)
{
    const int b = blockIdx.x >> 6;   // 0..7
    const int c = blockIdx.x & 63;   // 0..63
    float4*       kl = (float4*)(out + ((size_t)b * 128 + c) * 2048);
    const float4* ll = (const float4*)(out + ((size_t)b * 128 + 64 + c) * 2048);
    const int t = threadIdx.x;

    const float4 v0 = kl[t];
    const float4 v1 = kl[t + 256];
    float ss = v0.x*v0.x + v0.y*v0.y + v0.z*v0.z + v0.w*v0.w
             + v1.x*v1.x + v1.y*v1.y + v1.z*v1.z + v1.w*v1.w;
    #pragma unroll
    for (int off = 32; off; off >>= 1) ss += __shfl_xor(ss, off, 64);

    __shared__ float wsum[4];
    if ((t & 63) == 0) wsum[t >> 6] = ss;
    __syncthreads();
    const float tot = wsum[0] + wsum[1] + wsum[2] + wsum[3];
    const float rn  = 1.0f / sqrtf(tot);

    const float4 l0 = ll[t];
    const float4 l1 = ll[t + 256];
    kl[t]       = make_float4(fmaf(v0.x, rn, -l0.x), fmaf(v0.y, rn, -l0.y),
                              fmaf(v0.z, rn, -l0.z), fmaf(v0.w, rn, -l0.w));
    kl[t + 256] = make_float4(fmaf(v1.x, rn, -l1.x), fmaf(v1.y, rn, -l1.y),
                              fmaf(v1.z, rn, -l1.z), fmaf(v1.w, rn, -l1.w));
}

extern "C" void kernel_launch(void* const* d_in, const int* in_sizes, int n_in,
                              void* d_out, int out_size, void* d_ws, size_t ws_size,
                              hipStream_t stream) {
    const float* lc_x  = (const float*)d_in[0];   // 8*2048*64
    const float* knn_x = (const float*)d_in[1];   // 8*2048*32*6
    const float* fB    = (const float*)d_in[2];   // 7*32
    float* out = (float*)d_out;                   // 8*128*2048

    line_pass1<<<1024, 256, 0, stream>>>(lc_x, knn_x, fB, out);
    line_pass2<<<512, 256, 0, stream>>>(out);
}

// Round 8
// 22.155 us; speedup vs baseline: 1.0926x; 1.0926x over previous
//
#include <hip/hip_runtime.h>
#include <hip/hip_bf16.h>

// Problem constants: B=8, G=2048, K=32, N=6, C=64; fourier_B is (7,32)
// out: (B, 128, G) float32
//
// Algebraic simplifications (validated):
//  1) up/down == mean_k(knn_f) since e_x is constant over k, so
//     kl_raw = 2*mean_k(sin^5/cos^5(2*pi*x)).
//  2) x = fB . [p, p x n, p.n] is linear in p:
//     x = e0*p0 + e1*p1 + e2*p2 with per-channel e precomputed from fB and n.
//
// Round 8: block = 8 consecutive bg (4 waves x 2 bg) -> 2048 blocks = 8
// blocks/CU = 8 waves/SIMD (fixes round 7's grid-limited occupancy of 4).
// Output staged in klbuf[128][9] (odd pad -> conflict-free column writes),
// stored cooperatively as float4 rows (full-line L2 write merging).

#if __has_builtin(__builtin_amdgcn_fractf)
  #define FRACT(x) __builtin_amdgcn_fractf(x)
#else
  #define FRACT(x) ((x) - floorf(x))
#endif

__global__ __launch_bounds__(256, 8) void line_pass1(
    const float* __restrict__ lc_x,     // (B,G,64)
    const float* __restrict__ knn_x,    // (B,G,32,6)
    const float* __restrict__ fB,       // (7,32)
    float* __restrict__ out)            // (B,128,G)
{
    const int wave = threadIdx.x >> 6;
    const int lane = threadIdx.x & 63;
    const int half = lane >> 5;                 // 0: even k, 1: odd k
    const int jj   = lane & 31;                 // channel
    // bijective XCD swizzle: 2048 blocks, 8 XCDs, 256 blocks each
    const int sbid = (blockIdx.x & 7) * 256 + (blockIdx.x >> 3);
    const int bg0  = sbid * 8;                  // 8 consecutive bg per block
    const int b    = bg0 >> 11;
    const int g0   = bg0 & 2047;                // 8-aligned, never crosses b

    __shared__ __align__(16) float4 lv[4][2][32];   // [wave][i][k] p-vectors
    __shared__ float klbuf[128][9];                 // [channel][col], odd pad

    // fourier_B column for this lane's channel
    const float fb0 = fB[0*32 + jj];
    const float fb1 = fB[1*32 + jj];
    const float fb2 = fB[2*32 + jj];
    const float fb3 = fB[3*32 + jj];
    const float fb4 = fB[4*32 + jj];
    const float fb5 = fB[5*32 + jj];
    const float fb6 = fB[6*32 + jj];

    // ---- prefetch all global data for this wave's 2 bg
    float lcv[2], pp0[2], pp1[2], pp2[2];
    #pragma unroll
    for (int i = 0; i < 2; ++i) {
        const int bg = bg0 + wave * 2 + i;
        lcv[i] = lc_x[(size_t)bg * 64 + lane];          // coalesced
        if (half == 0) {
            const float* kp = knn_x + (size_t)bg * 192 + jj * 6;
            pp0[i] = kp[3]; pp1[i] = kp[4]; pp2[i] = kp[5];
        }
    }
    #pragma unroll
    for (int i = 0; i < 2; ++i) {
        if (half == 0)
            lv[wave][i][jj] = make_float4(pp0[i], pp1[i], pp2[i], 0.0f);
    }
    asm volatile("s_waitcnt lgkmcnt(0)" ::: "memory");  // wave-local, no barrier

    #pragma unroll
    for (int i = 0; i < 2; ++i) {
        const int bg  = bg0 + wave * 2 + i;
        const int col = wave * 2 + i;
        const float* lcr = lc_x + (size_t)bg * 64;
        const float n0 = lcr[3];                        // uniform -> s_load
        const float n1 = lcr[4];
        const float n2 = lcr[5];

        // lc_line: normalize over C=64
        float ssum = lcv[i] * lcv[i];
        #pragma unroll
        for (int off = 32; off; off >>= 1) ssum += __shfl_xor(ssum, off, 64);
        klbuf[64 + lane][col] = lcv[i] / sqrtf(ssum);

        // effective projection vector: x = e0*p0 + e1*p1 + e2*p2
        const float e0 = fmaf(fb6, n0, fmaf(fb5,  n1, fmaf(fb4, -n2, fb0)));
        const float e1 = fmaf(fb6, n1, fmaf(fb5, -n0, fmaf(fb3,  n2, fb1)));
        const float e2 = fmaf(fb6, n2, fmaf(fb4,  n0, fmaf(fb3, -n1, fb2)));

        float accS0 = 0.f, accS1 = 0.f, accC0 = 0.f, accC1 = 0.f;
        const float4* myk = &lv[wave][i][half];         // k = 2*t + half
        #pragma unroll
        for (int t = 0; t < 16; ++t) {
            const float4 p = myk[2 * t];                // broadcast ds_read_b128
            const float x = fmaf(e2, p.z, fmaf(e1, p.y, e0 * p.x));
            const float ts = FRACT(x);                  // revolutions in [0,1)
            const float tc = FRACT(x + 0.25f);
            const float s  = __builtin_amdgcn_sinf(ts); // sin(2*pi*x)
            const float cq = __builtin_amdgcn_sinf(tc); // cos(2*pi*x)
            const float s2 = s * s,   s4 = s2 * s2;
            const float q2 = cq * cq, q4 = q2 * q2;
            if (t & 1) { accS1 = fmaf(s4, s, accS1); accC1 = fmaf(q4, cq, accC1); }
            else       { accS0 = fmaf(s4, s, accS0); accC0 = fmaf(q4, cq, accC0); }
        }
        // merge even-k / odd-k halves across the lane32 boundary
        const float aS = accS0 + accS1;
        const float aC = accC0 + accC1;
        const float totS = aS + __shfl_xor(aS, 32, 64);
        const float totC = aC + __shfl_xor(aC, 32, 64);
        klbuf[lane][col] = (half ? totC : totS) * 0.0625f;  // 2*mean_k
    }

    __syncthreads();

    // cooperative coalesced store: thread t -> row c=t>>1, cols (t&1)*4..+3
    const int c  = threadIdx.x >> 1;
    const int j0 = (threadIdx.x & 1) * 4;
    const float4 o = make_float4(klbuf[c][j0], klbuf[c][j0+1],
                                 klbuf[c][j0+2], klbuf[c][j0+3]);
    *(float4*)(out + ((size_t)b * 128 + c) * 2048 + g0 + j0) = o;
}

__global__ __launch_bounds__(256) void line_pass2(float* __restrict__ out)
{
    const int b = blockIdx.x >> 6;   // 0..7
    const int c = blockIdx.x & 63;   // 0..63
    float4*       kl = (float4*)(out + ((size_t)b * 128 + c) * 2048);
    const float4* ll = (const float4*)(out + ((size_t)b * 128 + 64 + c) * 2048);
    const int t = threadIdx.x;

    const float4 v0 = kl[t];
    const float4 v1 = kl[t + 256];
    float ss = v0.x*v0.x + v0.y*v0.y + v0.z*v0.z + v0.w*v0.w
             + v1.x*v1.x + v1.y*v1.y + v1.z*v1.z + v1.w*v1.w;
    #pragma unroll
    for (int off = 32; off; off >>= 1) ss += __shfl_xor(ss, off, 64);

    __shared__ float wsum[4];
    if ((t & 63) == 0) wsum[t >> 6] = ss;
    __syncthreads();
    const float tot = wsum[0] + wsum[1] + wsum[2] + wsum[3];
    const float rn  = 1.0f / sqrtf(tot);

    const float4 l0 = ll[t];
    const float4 l1 = ll[t + 256];
    kl[t]       = make_float4(fmaf(v0.x, rn, -l0.x), fmaf(v0.y, rn, -l0.y),
                              fmaf(v0.z, rn, -l0.z), fmaf(v0.w, rn, -l0.w));
    kl[t + 256] = make_float4(fmaf(v1.x, rn, -l1.x), fmaf(v1.y, rn, -l1.y),
                              fmaf(v1.z, rn, -l1.z), fmaf(v1.w, rn, -l1.w));
}

extern "C" void kernel_launch(void* const* d_in, const int* in_sizes, int n_in,
                              void* d_out, int out_size, void* d_ws, size_t ws_size,
                              hipStream_t stream) {
    const float* lc_x  = (const float*)d_in[0];   // 8*2048*64
    const float* knn_x = (const float*)d_in[1];   // 8*2048*32*6
    const float* fB    = (const float*)d_in[2];   // 7*32
    float* out = (float*)d_out;                   // 8*128*2048

    line_pass1<<<2048, 256, 0, stream>>>(lc_x, knn_x, fB, out);
    line_pass2<<<512, 256, 0, stream>>>(out);
}

// Round 9
// 21.489 us; speedup vs baseline: 1.1265x; 1.0310x over previous
//
#include <hip/hip_runtime.h>
#include <hip/hip_bf16.h>

// Problem constants: B=8, G=2048, K=32, N=6, C=64; fourier_B is (7,32)
// out: (B, 128, G) float32
//
// Algebraic simplifications (validated):
//  1) up/down == mean_k(knn_f) since e_x is constant over k, so
//     kl_raw = 2*mean_k(sin^5/cos^5(2*pi*x)).
//  2) x = fB . [p, p x n, p.n] is linear in p:
//     x = e0*p0 + e1*p1 + e2*p2 with per-channel e precomputed from fB and n.
//
// Round 9: fully-coalesced staging. Each wave owns 2 bg; its global traffic
// (2x64 lc floats + 2x192 knn floats = 128 float4) is loaded as exactly TWO
// coalesced float4 loads per lane into wave-local LDS, then consumed via b32
// broadcast reads. No scalar gathers, no cross-wave barrier for staging.

#if __has_builtin(__builtin_amdgcn_fractf)
  #define FRACT(x) __builtin_amdgcn_fractf(x)
#else
  #define FRACT(x) ((x) - floorf(x))
#endif

__global__ __launch_bounds__(256, 8) void line_pass1(
    const float* __restrict__ lc_x,     // (B,G,64)
    const float* __restrict__ knn_x,    // (B,G,32,6)
    const float* __restrict__ fB,       // (7,32)
    float* __restrict__ out)            // (B,128,G)
{
    const int wave = threadIdx.x >> 6;
    const int lane = threadIdx.x & 63;
    const int half = lane >> 5;                 // 0: even k, 1: odd k
    const int jj   = lane & 31;                 // channel
    // bijective XCD swizzle: 2048 blocks, 8 XCDs, 256 blocks each
    const int sbid = (blockIdx.x & 7) * 256 + (blockIdx.x >> 3);
    const int bg0  = sbid * 8;                  // 8 consecutive bg per block
    const int b    = bg0 >> 11;
    const int g0   = bg0 & 2047;                // 8-aligned, never crosses b

    __shared__ __align__(16) float lcbuf[4][128];    // [wave][2 rows x 64]
    __shared__ __align__(16) float knbuf[4][384];    // [wave][2 rows x 192]
    __shared__ float klbuf[128][9];                  // [channel][col], odd pad

    // fourier_B column for this lane's channel
    const float fb0 = fB[0*32 + jj];
    const float fb1 = fB[1*32 + jj];
    const float fb2 = fB[2*32 + jj];
    const float fb3 = fB[3*32 + jj];
    const float fb4 = fB[4*32 + jj];
    const float fb5 = fB[5*32 + jj];
    const float fb6 = fB[6*32 + jj];

    // ---- coalesced staging: 2 float4 loads per lane, wave-local LDS
    {
        const float4* lcsrc = (const float4*)(lc_x  + (size_t)(bg0 + wave * 2) * 64);
        const float4* knsrc = (const float4*)(knn_x + (size_t)(bg0 + wave * 2) * 192);
        float4* lcb4 = (float4*)&lcbuf[wave][0];   // 32 float4
        float4* knb4 = (float4*)&knbuf[wave][0];   // 96 float4
        if (lane < 32) lcb4[lane]      = lcsrc[lane];
        else           knb4[lane + 32] = knsrc[lane + 32];
        knb4[lane] = knsrc[lane];
    }
    // producer and consumer are the same wave -> wave-local wait, no barrier
    asm volatile("s_waitcnt vmcnt(0) lgkmcnt(0)" ::: "memory");

    #pragma unroll
    for (int i = 0; i < 2; ++i) {
        const int col = wave * 2 + i;
        const float* lcr = &lcbuf[wave][i * 64];
        const float* knr = &knbuf[wave][i * 192];

        // lc_normal = raw lc[3:6] (broadcast b32 reads)
        const float n0 = lcr[3];
        const float n1 = lcr[4];
        const float n2 = lcr[5];

        // lc_line: normalize over C=64
        const float myv = lcr[lane];
        float ssum = myv * myv;
        #pragma unroll
        for (int off = 32; off; off >>= 1) ssum += __shfl_xor(ssum, off, 64);
        klbuf[64 + lane][col] = myv / sqrtf(ssum);

        // effective projection vector: x = e0*p0 + e1*p1 + e2*p2
        const float e0 = fmaf(fb6, n0, fmaf(fb5,  n1, fmaf(fb4, -n2, fb0)));
        const float e1 = fmaf(fb6, n1, fmaf(fb5, -n0, fmaf(fb3,  n2, fb1)));
        const float e2 = fmaf(fb6, n2, fmaf(fb4,  n0, fmaf(fb3, -n1, fb2)));

        float accS0 = 0.f, accS1 = 0.f, accC0 = 0.f, accC1 = 0.f;
        const float* myk = knr + half * 6;              // k = 2*t + half
        #pragma unroll
        for (int t = 0; t < 16; ++t) {
            // broadcast b32 reads, uniform address per half-wave
            const float p0 = myk[t * 12 + 3];
            const float p1 = myk[t * 12 + 4];
            const float p2 = myk[t * 12 + 5];
            const float x = fmaf(e2, p2, fmaf(e1, p1, e0 * p0));
            const float ts = FRACT(x);                  // revolutions in [0,1)
            const float tc = FRACT(x + 0.25f);
            const float s  = __builtin_amdgcn_sinf(ts); // sin(2*pi*x)
            const float cq = __builtin_amdgcn_sinf(tc); // cos(2*pi*x)
            const float s2 = s * s,   s4 = s2 * s2;
            const float q2 = cq * cq, q4 = q2 * q2;
            if (t & 1) { accS1 = fmaf(s4, s, accS1); accC1 = fmaf(q4, cq, accC1); }
            else       { accS0 = fmaf(s4, s, accS0); accC0 = fmaf(q4, cq, accC0); }
        }
        // merge even-k / odd-k halves across the lane32 boundary
        const float aS = accS0 + accS1;
        const float aC = accC0 + accC1;
        const float totS = aS + __shfl_xor(aS, 32, 64);
        const float totC = aC + __shfl_xor(aC, 32, 64);
        klbuf[lane][col] = (half ? totC : totS) * 0.0625f;  // 2*mean_k
    }

    __syncthreads();

    // cooperative coalesced store: thread t -> row c=t>>1, cols (t&1)*4..+3
    const int c  = threadIdx.x >> 1;
    const int j0 = (threadIdx.x & 1) * 4;
    const float4 o = make_float4(klbuf[c][j0], klbuf[c][j0+1],
                                 klbuf[c][j0+2], klbuf[c][j0+3]);
    *(float4*)(out + ((size_t)b * 128 + c) * 2048 + g0 + j0) = o;
}

__global__ __launch_bounds__(256) void line_pass2(float* __restrict__ out)
{
    const int b = blockIdx.x >> 6;   // 0..7
    const int c = blockIdx.x & 63;   // 0..63
    float4*       kl = (float4*)(out + ((size_t)b * 128 + c) * 2048);
    const float4* ll = (const float4*)(out + ((size_t)b * 128 + 64 + c) * 2048);
    const int t = threadIdx.x;

    const float4 v0 = kl[t];
    const float4 v1 = kl[t + 256];
    float ss = v0.x*v0.x + v0.y*v0.y + v0.z*v0.z + v0.w*v0.w
             + v1.x*v1.x + v1.y*v1.y + v1.z*v1.z + v1.w*v1.w;
    #pragma unroll
    for (int off = 32; off; off >>= 1) ss += __shfl_xor(ss, off, 64);

    __shared__ float wsum[4];
    if ((t & 63) == 0) wsum[t >> 6] = ss;
    __syncthreads();
    const float tot = wsum[0] + wsum[1] + wsum[2] + wsum[3];
    const float rn  = 1.0f / sqrtf(tot);

    const float4 l0 = ll[t];
    const float4 l1 = ll[t + 256];
    kl[t]       = make_float4(fmaf(v0.x, rn, -l0.x), fmaf(v0.y, rn, -l0.y),
                              fmaf(v0.z, rn, -l0.z), fmaf(v0.w, rn, -l0.w));
    kl[t + 256] = make_float4(fmaf(v1.x, rn, -l1.x), fmaf(v1.y, rn, -l1.y),
                              fmaf(v1.z, rn, -l1.z), fmaf(v1.w, rn, -l1.w));
}

extern "C" void kernel_launch(void* const* d_in, const int* in_sizes, int n_in,
                              void* d_out, int out_size, void* d_ws, size_t ws_size,
                              hipStream_t stream) {
    const float* lc_x  = (const float*)d_in[0];   // 8*2048*64
    const float* knn_x = (const float*)d_in[1];   // 8*2048*32*6
    const float* fB    = (const float*)d_in[2];   // 7*32
    float* out = (float*)d_out;                   // 8*128*2048

    line_pass1<<<2048, 256, 0, stream>>>(lc_x, knn_x, fB, out);
    line_pass2<<<512, 256, 0, stream>>>(out);
}